// Round 3
// baseline (1466.681 us; speedup 1.0000x reference)
//
#include <hip/hip_runtime.h>

// Problem constants
#define N_NODESC 50000
#define N_EDGESC 800000
#define EPSF 1e-5
#define NTILES 1563                 // ceil(50000/32)
#define NKEYS  (NTILES * 512)       // 800256 = (tile,combo,dloc) keys
#define NHBLK  3126                 // NKEYS/256 exactly
#define NEBLK  3125                 // 800000/256 exactly

// ---- ws layout (bytes), total ~52.3 MB ----
#define WS_SCALE 0
#define WS_SHIFT 256
#define WS_BSUM  512                // 3126 int
#define WS_PBUF  13056              // NTILES*128 f32 = 800256 B
#define WS_HIST  813312             // NKEYS int
#define WS_SEG   4014336            // (NKEYS+1) int
#define WS_FILL  7215616            // NKEYS int
#define WS_ESRC  10416640           // 800000 int
#define WS_MT    13616640           // 16*64*64 f32 = 256 KB
#define WS_HB    13878784           // 50000*64 f32
#define WS_OUTB  26678784
#define WS_HA    39478784

__device__ __forceinline__ int edge_key(int d, int c) {
    return ((d >> 5) << 9) + (c << 5) + (d & 31);
}

// ---------------- histogram over (tile, combo, dloc) keys ----------------
__global__ __launch_bounds__(256)
void k_khist(const int* __restrict__ src, const int* __restrict__ dst,
             const int* __restrict__ labels, const int* __restrict__ bidx,
             int* __restrict__ hist)
{
    const int e = blockIdx.x * 256 + threadIdx.x;
    if (e >= N_EDGESC) return;
    const int s = src[e], d = dst[e];
    const int c = (labels[d] * 2 + labels[s]) * 4 + bidx[e];
    atomicAdd(&hist[edge_key(d, c)], 1);
}

// ---------------- 3-level exclusive scan of hist -> seg ----------------
__global__ __launch_bounds__(256)
void k_bsum2(const int* __restrict__ hist, int* __restrict__ bsum)
{
    __shared__ int s[256];
    const int i = blockIdx.x * 256 + threadIdx.x;
    s[threadIdx.x] = hist[i];
    __syncthreads();
    for (int off = 128; off > 0; off >>= 1) {
        if (threadIdx.x < off) s[threadIdx.x] += s[threadIdx.x + off];
        __syncthreads();
    }
    if (threadIdx.x == 0) bsum[blockIdx.x] = s[0];
}

__global__ __launch_bounds__(1024)
void k_bscan2(int* __restrict__ bsum)   // in-place exclusive scan of NHBLK entries
{
    __shared__ int s[1024];
    const int t = threadIdx.x;
    int v[4]; int tot = 0;
#pragma unroll
    for (int j = 0; j < 4; ++j) {
        const int i = t * 4 + j;
        v[j] = (i < NHBLK) ? bsum[i] : 0;
        tot += v[j];
    }
    s[t] = tot; __syncthreads();
    for (int off = 1; off < 1024; off <<= 1) {
        const int x = (t >= off) ? s[t - off] : 0;
        __syncthreads();
        s[t] += x;
        __syncthreads();
    }
    int base = s[t] - tot;   // exclusive
#pragma unroll
    for (int j = 0; j < 4; ++j) {
        const int i = t * 4 + j;
        if (i < NHBLK) bsum[i] = base;
        base += v[j];
    }
}

__global__ __launch_bounds__(256)
void k_escan2(const int* __restrict__ hist, const int* __restrict__ bsum,
              int* __restrict__ seg)
{
    __shared__ int s[256];
    const int t = threadIdx.x;
    const int i = blockIdx.x * 256 + t;
    const int v = hist[i];
    s[t] = v; __syncthreads();
    for (int off = 1; off < 256; off <<= 1) {
        const int x = (t >= off) ? s[t - off] : 0;
        __syncthreads();
        s[t] += x;
        __syncthreads();
    }
    const int incl = s[t];
    seg[i] = bsum[blockIdx.x] + incl - v;
    if (i == NKEYS - 1) seg[NKEYS] = bsum[blockIdx.x] + incl;
}

// ---------------- scatter src ids into key-sorted order ----------------
__global__ __launch_bounds__(256)
void k_scat(const int* __restrict__ src, const int* __restrict__ dst,
            const int* __restrict__ labels, const int* __restrict__ bidx,
            const int* __restrict__ seg, int* __restrict__ fill,
            int* __restrict__ esrc_s)
{
    const int e = blockIdx.x * 256 + threadIdx.x;
    if (e >= N_EDGESC) return;
    const int s = src[e], d = dst[e];
    const int c = (labels[d] * 2 + labels[s]) * 4 + bidx[e];
    const int k = edge_key(d, c);
    const int pos = seg[k] + atomicAdd(&fill[k], 1);
    esrc_s[pos] = s;
}

// ---------------- Mt[c][k][o] = M[c][o][k] ----------------
__global__ __launch_bounds__(256)
void k_mt(const float* __restrict__ M, float* __restrict__ Mt)
{
    const int c = blockIdx.x;
    for (int idx = threadIdx.x; idx < 4096; idx += 256) {
        const int o = idx >> 6, k = idx & 63;
        Mt[c * 4096 + k * 64 + o] = M[c * 4096 + idx];
    }
}

// ---------------- h = in @ W + b ----------------
__global__ __launch_bounds__(256)
void k_h(const float* __restrict__ in, const float* __restrict__ W,
         const float* __restrict__ b, float* __restrict__ h, const int F)
{
    const int t = blockIdx.x * 256 + threadIdx.x;
    if (t >= N_NODESC * 64) return;
    const int n = t >> 6, e = t & 63;
    const float* __restrict__ xr = in + (long)n * F;
    float acc = b[e];
    for (int f = 0; f < F; f += 4) {
        acc += xr[f]     * W[f * 64 + e];
        acc += xr[f + 1] * W[(f + 1) * 64 + e];
        acc += xr[f + 2] * W[(f + 2) * 64 + e];
        acc += xr[f + 3] * W[(f + 3) * 64 + e];
    }
    h[t] = acc;
}

// ---------------- per-tile: gather S + 16x dense matmul + residual + LN partials ----
__global__ __launch_bounds__(256, 4)
void k_edge(const float* __restrict__ h, const int* __restrict__ esrc_s,
            const int* __restrict__ seg, const float* __restrict__ Mt,
            float* __restrict__ outb, float* __restrict__ pbuf)
{
    __shared__ alignas(16) float S[64][36];    // [feat_in][dst_local], pad 36
    __shared__ float ssum[8][64];
    __shared__ float ssq[8][64];
    const int tid  = threadIdx.x;
    const int w    = tid >> 6, lane = tid & 63;
    const int esub = lane >> 4, k4 = lane & 15;
    const int d0   = (tid & 7) * 4;            // 0..28
    const int o0   = (tid >> 3) * 2;           // 0..62
    const int tile = blockIdx.x;
    const float4* __restrict__ h4 = (const float4*)h;

    float C00 = 0, C01 = 0, C10 = 0, C11 = 0, C20 = 0, C21 = 0, C30 = 0, C31 = 0;

    for (int c = 0; c < 16; ++c) {
        // ---- gather phase: wave w owns dst locals [8w, 8w+8) ----
        const int base = tile * 512 + c * 32 + w * 8;
        int pprev = seg[base];
#pragma unroll
        for (int dd = 0; dd < 8; ++dd) {
            const int pnext = seg[base + dd + 1];
            float ax = 0.f, ay = 0.f, az = 0.f, aw = 0.f;
            for (int p = pprev + esub; p < pnext; p += 4) {
                const int s = esrc_s[p];
                const float4 hv = h4[s * 16 + k4];
                ax += hv.x; ay += hv.y; az += hv.z; aw += hv.w;
            }
            ax += __shfl_xor(ax, 16); ay += __shfl_xor(ay, 16);
            az += __shfl_xor(az, 16); aw += __shfl_xor(aw, 16);
            ax += __shfl_xor(ax, 32); ay += __shfl_xor(ay, 32);
            az += __shfl_xor(az, 32); aw += __shfl_xor(aw, 32);
            const int dloc = w * 8 + dd;
            if (lane < 16) {
                S[4 * k4 + 0][dloc] = ax;
                S[4 * k4 + 1][dloc] = ay;
                S[4 * k4 + 2][dloc] = az;
                S[4 * k4 + 3][dloc] = aw;
            }
            pprev = pnext;
        }
        __syncthreads();

        // ---- matmul phase: C[4d][2o] += S^T * Mt[c] ----
        const float* __restrict__ Mtc = Mt + c * 4096;
#pragma unroll 16
        for (int k = 0; k < 64; ++k) {
            const float4 s4 = *(const float4*)&S[k][d0];
            const float2 m2 = *(const float2*)&Mtc[k * 64 + o0];
            C00 += s4.x * m2.x; C01 += s4.x * m2.y;
            C10 += s4.y * m2.x; C11 += s4.y * m2.y;
            C20 += s4.z * m2.x; C21 += s4.z * m2.y;
            C30 += s4.w * m2.x; C31 += s4.w * m2.y;
        }
        __syncthreads();
    }

    // ---- epilogue: residual add + store + LN partial stats ----
    float s10 = 0.f, s11 = 0.f, s20 = 0.f, s21 = 0.f;
    const int dbase = tile * 32 + d0;
    const float cc[4][2] = {{C00, C01}, {C10, C11}, {C20, C21}, {C30, C31}};
#pragma unroll
    for (int i = 0; i < 4; ++i) {
        const int d = dbase + i;
        if (d < N_NODESC) {
            const float2 hv = *(const float2*)&h[(long)d * 64 + o0];
            const float v0 = cc[i][0] + hv.x;
            const float v1 = cc[i][1] + hv.y;
            float2 st; st.x = v0; st.y = v1;
            *(float2*)&outb[(long)d * 64 + o0] = st;
            s10 += v0; s11 += v1; s20 += v0 * v0; s21 += v1 * v1;
        }
    }
    ssum[tid & 7][o0] = s10; ssum[tid & 7][o0 + 1] = s11;
    ssq[tid & 7][o0]  = s20; ssq[tid & 7][o0 + 1]  = s21;
    __syncthreads();
    if (tid < 64) {
        float t1 = 0.f, t2 = 0.f;
#pragma unroll
        for (int dg = 0; dg < 8; ++dg) { t1 += ssum[dg][tid]; t2 += ssq[dg][tid]; }
        pbuf[blockIdx.x * 128 + tid] = t1;
        pbuf[blockIdx.x * 128 + 64 + tid] = t2;
    }
}

// ---------------- reduce LN partials -> scale/shift ----------------
__global__ __launch_bounds__(1024)
void k_norm2(const float* __restrict__ pbuf, const float* __restrict__ g,
             const float* __restrict__ be, float* __restrict__ scale,
             float* __restrict__ shift)
{
    __shared__ float s[1024];
    const int t = threadIdx.x, j = t & 127, gg = t >> 7;
    float a = 0.f;
    for (int b = gg; b < NTILES; b += 8) a += pbuf[b * 128 + j];
    s[t] = a;
    __syncthreads();
    if (t < 128) {
        float tot = 0.f;
#pragma unroll
        for (int k = 0; k < 8; ++k) tot += s[j + 128 * k];
        s[t] = tot;
    }
    __syncthreads();
    if (t < 64) {
        const double mu  = (double)s[t] / (double)N_NODESC;
        const double var = (double)s[64 + t] / (double)N_NODESC - mu * mu;
        const double sc  = (double)g[t] / sqrt(var + EPSF);
        scale[t] = (float)sc;
        shift[t] = (float)((double)be[t] - mu * sc);
    }
}

// ---------------- LN apply + relu ----------------
__global__ __launch_bounds__(256)
void k_apply(const float* __restrict__ agg, const float* __restrict__ scale,
             const float* __restrict__ shift, float* __restrict__ hout)
{
    const int t = blockIdx.x * 256 + threadIdx.x;
    if (t >= N_NODESC * 64) return;
    const int e = t & 63;
    const float v = agg[t] * scale[e] + shift[e];
    hout[t] = fmaxf(v, 0.f);
}

// ---------------- final projection (LN apply fused) ----------------
__global__ __launch_bounds__(256)
void k_out(const float* __restrict__ outb, const float* __restrict__ scale,
           const float* __restrict__ shift, const float* __restrict__ resW,
           const float* __restrict__ resb, float* __restrict__ out)
{
    const int n = blockIdx.x * 256 + threadIdx.x;
    if (n >= N_NODESC) return;
    float a0 = resb[0], a1 = resb[1];
    const float* __restrict__ r = outb + (long)n * 64;
#pragma unroll 8
    for (int e = 0; e < 64; ++e) {
        const float v = fmaxf(r[e] * scale[e] + shift[e], 0.f);
        a0 += v * resW[2 * e];
        a1 += v * resW[2 * e + 1];
    }
    out[2 * n] = a0;
    out[2 * n + 1] = a1;
}

extern "C" void kernel_launch(void* const* d_in, const int* in_sizes, int n_in,
                              void* d_out, int out_size, void* d_ws, size_t ws_size,
                              hipStream_t stream)
{
    const float* x      = (const float*)d_in[0];
    const float* M      = (const float*)d_in[1];   // (16,64,64)
    const int*   src    = (const int*)d_in[2];
    const int*   dst    = (const int*)d_in[3];
    const int*   labels = (const int*)d_in[4];
    const int*   bidx   = (const int*)d_in[5];
    const float* resW   = (const float*)d_in[18];
    const float* resb   = (const float*)d_in[19];
    float* out = (float*)d_out;

    char* ws = (char*)d_ws;
    float* scale  = (float*)(ws + WS_SCALE);
    float* shift  = (float*)(ws + WS_SHIFT);
    int*   bsum   = (int*)(ws + WS_BSUM);
    float* pbuf   = (float*)(ws + WS_PBUF);
    int*   hist   = (int*)(ws + WS_HIST);
    int*   seg    = (int*)(ws + WS_SEG);
    int*   fill   = (int*)(ws + WS_FILL);
    int*   esrc_s = (int*)(ws + WS_ESRC);
    float* Mt     = (float*)(ws + WS_MT);
    float* hB     = (float*)(ws + WS_HB);
    float* outb   = (float*)(ws + WS_OUTB);
    float* hA     = (float*)(ws + WS_HA);

    const int NB64 = (N_NODESC * 64 + 255) / 256;  // 12500

    // ---- preprocessing (labels/bidx/src/dst constant across layers) ----
    hipMemsetAsync(hist, 0, (size_t)NKEYS * 4, stream);
    hipMemsetAsync(fill, 0, (size_t)NKEYS * 4, stream);
    k_khist<<<NEBLK, 256, 0, stream>>>(src, dst, labels, bidx, hist);
    k_bsum2<<<NHBLK, 256, 0, stream>>>(hist, bsum);
    k_bscan2<<<1, 1024, 0, stream>>>(bsum);
    k_escan2<<<NHBLK, 256, 0, stream>>>(hist, bsum, seg);
    k_scat<<<NEBLK, 256, 0, stream>>>(src, dst, labels, bidx, seg, fill, esrc_s);
    k_mt<<<16, 256, 0, stream>>>(M, Mt);

    for (int l = 0; l < 3; ++l) {
        const float* W  = (const float*)d_in[6 + 4 * l];
        const float* b  = (const float*)d_in[7 + 4 * l];
        const float* g  = (const float*)d_in[8 + 4 * l];
        const float* be = (const float*)d_in[9 + 4 * l];

        if (l == 0) {
            k_h<<<NB64, 256, 0, stream>>>(x, W, b, hB, 128);
        } else {
            k_apply<<<NB64, 256, 0, stream>>>(outb, scale, shift, hA);
            k_h<<<NB64, 256, 0, stream>>>(hA, W, b, hB, 64);
        }
        k_edge<<<NTILES, 256, 0, stream>>>(hB, esrc_s, seg, Mt, outb, pbuf);
        k_norm2<<<1, 1024, 0, stream>>>(pbuf, g, be, scale, shift);
    }
    k_out<<<(N_NODESC + 255) / 256, 256, 0, stream>>>(outb, scale, shift, resW, resb, out);
    (void)in_sizes; (void)n_in; (void)out_size; (void)ws_size;
}